// Round 1
// baseline (3138.417 us; speedup 1.0000x reference)
//
#include <hip/hip_runtime.h>
#include <hip/hip_fp16.h>

// ---------------- workspace layout (bytes) ----------------
#define WS_X0U   0            // 256*64*4        = 65536
#define WS_G     65536        // 256*128*64*4    = 8388608   G[c][o][p]
#define WS_W2A   8454144      // 128*256*4       = 131072    sum_k W1^2 [o][c]
#define WS_W2B   8585216      // 64*128*4        = 32768     sum_k W2^2 [o][c]
#define WS_S1    8617984      // 2048*256*4      = 2097152   style1
#define WS_S2    10715136     // 2048*128*4      = 1048576   style2
#define WS_D1    11763712     // 2048*128*4      = 1048576   demod1
#define WS_D2    12812288     // 2048*64*4       = 524288    demod2
#define WS_X1    13336576     // 2048*128*64*2   = 33554432  x1 (f16)
// total ~44.7 MB

// bilinear x2, half-pixel centers (torch align_corners=False / jax bilinear)
__device__ __forceinline__ void up_wi(int j, int S, int& i0, int& i1,
                                      float& w0, float& w1) {
  int m = j >> 1;
  if (j & 1) { i0 = m; i1 = (m + 1 < S) ? m + 1 : S - 1; w0 = 0.75f; w1 = 0.25f; }
  else       { i0 = (m - 1 >= 0) ? m - 1 : 0; i1 = m;     w0 = 0.25f; w1 = 0.75f; }
}

// ---------------- K0: init conv + lrelu + upsample 4->8 ----------------
// grid 256 (out channel), block 64
__global__ __launch_bounds__(64) void k_init(const float* __restrict__ ic,
    const float* __restrict__ w0c, const float* __restrict__ b0,
    float* __restrict__ x0u) {
  int o = blockIdx.x, t = threadIdx.x;
  __shared__ float part[4][16];
  __shared__ float x4[16];
  int pix = t & 15, cg = t >> 4;
  int py = pix >> 2, px = pix & 3;
  float acc = 0.f;
  for (int c = cg * 128; c < cg * 128 + 128; ++c) {
    const float* wp = w0c + (o * 512 + c) * 9;
    const float* xp = ic + c * 16;
#pragma unroll
    for (int dy = 0; dy < 3; ++dy) {
      int iy = py + dy - 1;
      if ((unsigned)iy >= 4u) continue;
#pragma unroll
      for (int dx = 0; dx < 3; ++dx) {
        int ix = px + dx - 1;
        if ((unsigned)ix >= 4u) continue;
        acc += wp[dy * 3 + dx] * xp[iy * 4 + ix];
      }
    }
  }
  part[cg][pix] = acc;
  __syncthreads();
  if (t < 16) {
    float v = part[0][t] + part[1][t] + part[2][t] + part[3][t] + b0[o];
    x4[t] = (v >= 0.f) ? v : 0.2f * v;
  }
  __syncthreads();
  int oy = t >> 3, ox = t & 7;
  int y0, y1, xx0, xx1; float wy0, wy1, wx0, wx1;
  up_wi(oy, 4, y0, y1, wy0, wy1);
  up_wi(ox, 4, xx0, xx1, wx0, wx1);
  float v = wy0 * (wx0 * x4[y0 * 4 + xx0] + wx1 * x4[y0 * 4 + xx1])
          + wy1 * (wx0 * x4[y1 * 4 + xx0] + wx1 * x4[y1 * 4 + xx1]);
  x0u[o * 64 + t] = v;
}

// ---------------- K0b: G[c][o][p] = conv(x0u, W1) per (o,c); + w2 tables --
// grid 128 (o), block 256
__global__ __launch_bounds__(256) void k_prep(const float* __restrict__ w1c,
    const float* __restrict__ w2c, const float* __restrict__ x0u,
    float* __restrict__ G, float* __restrict__ w2a, float* __restrict__ w2b) {
  int o = blockIdx.x, t = threadIdx.x;
  int p = t & 63, cg = t >> 6;
  int py = p >> 3, px = p & 7;
  for (int jc = 0; jc < 64; ++jc) {
    int c = cg * 64 + jc;
    const float* wp = w1c + (o * 256 + c) * 9;
    const float* xp = x0u + c * 64;
    float acc = 0.f;
#pragma unroll
    for (int dy = 0; dy < 3; ++dy) {
      int iy = py + dy - 1;
      if ((unsigned)iy >= 8u) continue;
#pragma unroll
      for (int dx = 0; dx < 3; ++dx) {
        int ix = px + dx - 1;
        if ((unsigned)ix >= 8u) continue;
        acc += wp[dy * 3 + dx] * xp[iy * 8 + ix];
      }
    }
    G[(c * 128 + o) * 64 + p] = acc;
  }
  {
    const float* wp = w1c + (o * 256 + t) * 9;
    float s = 0.f;
#pragma unroll
    for (int k = 0; k < 9; ++k) s += wp[k] * wp[k];
    w2a[o * 256 + t] = s;
  }
  if (o < 64 && t < 128) {
    const float* wp = w2c + (o * 128 + t) * 9;
    float s = 0.f;
#pragma unroll
    for (int k = 0; k < 9; ++k) s += wp[k] * wp[k];
    w2b[o * 128 + t] = s;
  }
}

// ---------------- K_style: styles + demods, 16 batches/block -------------
// grid 128, block 256
__global__ __launch_bounds__(256) void k_style(const float* __restrict__ w,
    const float* __restrict__ a1w, const float* __restrict__ a1b,
    const float* __restrict__ a2w, const float* __restrict__ a2b,
    const float* __restrict__ w2a, const float* __restrict__ w2b,
    float* __restrict__ s1, float* __restrict__ s2,
    float* __restrict__ d1, float* __restrict__ d2) {
  int b0 = blockIdx.x * 16, t = threadIdx.x;
  __shared__ float wl[16][512];
  __shared__ float sl[16][384];
  for (int i = t; i < 16 * 512; i += 256) {
    int bi = i >> 9, k = i & 511;
    wl[bi][k] = w[(b0 + bi) * 512 + k];
  }
  __syncthreads();
  int bi = t >> 4, fg = t & 15;
  for (int j = 0; j < 24; ++j) {
    int f = fg + 16 * j;
    const float* ap; float bias;
    if (f < 256) { ap = a1w + f * 512; bias = a1b[f]; }
    else         { ap = a2w + (f - 256) * 512; bias = a2b[f - 256]; }
    float acc = bias;
    for (int k = 0; k < 512; k += 4) {
      float4 wv = *(const float4*)&wl[bi][k];
      float4 av = *(const float4*)&ap[k];
      acc += wv.x * av.x + wv.y * av.y + wv.z * av.z + wv.w * av.w;
    }
    sl[bi][f] = acc;
    if (f < 256) s1[(b0 + bi) * 256 + f] = acc;
    else         s2[(b0 + bi) * 128 + (f - 256)] = acc;
  }
  __syncthreads();
  for (int j = 0; j < 8; ++j) {
    int oo = fg + 16 * j;                     // 0..127
    float acc = 1e-8f;
    const float* w2p = w2a + oo * 256;
    for (int c = 0; c < 256; ++c) { float s = sl[bi][c]; acc += s * s * w2p[c]; }
    d1[(b0 + bi) * 128 + oo] = rsqrtf(acc);
  }
  for (int j = 0; j < 4; ++j) {
    int oo = fg + 16 * j;                     // 0..63
    float acc = 1e-8f;
    const float* w2p = w2b + oo * 128;
    for (int c = 0; c < 128; ++c) { float s = sl[bi][256 + c]; acc += s * s * w2p[c]; }
    d2[(b0 + bi) * 64 + oo] = rsqrtf(acc);
  }
}

// ---------------- K_l1: y1 = style1 x G, fused demod/bias/lrelu, f16 out --
// M=2048(b) N=8192(o*64+p) K=256; tile 64x256; grid (32,32), block 256
__global__ __launch_bounds__(256) void k_l1(const float* __restrict__ s1,
    const float* __restrict__ G, const float* __restrict__ d1,
    const float* __restrict__ c1b, __half* __restrict__ x1) {
  int n0 = blockIdx.x * 256, b0 = blockIdx.y * 64;
  int t = threadIdx.x;
  __shared__ float As[32][65];
  __shared__ float Bs[32][256];
  float acc[8][8] = {};
  int rb = t >> 5, cb = t & 31;
  for (int kc = 0; kc < 256; kc += 32) {
    {
      int bb = t >> 2, kg = t & 3;
      const float* src = s1 + (b0 + bb) * 256 + kc + kg * 8;
#pragma unroll
      for (int j = 0; j < 8; ++j) As[kg * 8 + j][bb] = src[j];
    }
    {
      int kk = t >> 3, col0 = (t & 7) * 32;
      const float* src = G + (kc + kk) * 8192 + n0 + col0;
      float* dst = &Bs[kk][col0];
#pragma unroll
      for (int j = 0; j < 32; j += 4)
        *(float4*)&dst[j] = *(const float4*)&src[j];
    }
    __syncthreads();
#pragma unroll
    for (int k = 0; k < 32; ++k) {
      float a[8], bb[8];
#pragma unroll
      for (int i = 0; i < 8; ++i) a[i] = As[k][rb * 8 + i];
#pragma unroll
      for (int j = 0; j < 8; ++j) bb[j] = Bs[k][cb * 8 + j];
#pragma unroll
      for (int i = 0; i < 8; ++i)
#pragma unroll
        for (int j = 0; j < 8; ++j) acc[i][j] += a[i] * bb[j];
    }
    __syncthreads();
  }
  int o = (n0 >> 6) + (cb >> 3);
  int p = (cb & 7) * 8;
  float bias = c1b[o];
#pragma unroll
  for (int i = 0; i < 8; ++i) {
    int b = b0 + rb * 8 + i;
    float dm = d1[b * 128 + o];
    alignas(16) __half hv[8];
#pragma unroll
    for (int j = 0; j < 8; ++j) {
      float v = acc[i][j] * dm + bias;
      v = (v >= 0.f) ? v : 0.2f * v;
      hv[j] = __float2half(v);
    }
    *(float4*)&x1[(b * 128 + o) * 64 + p] = *(const float4*)hv;
  }
}

// ---------------- K_l2: per-batch upsample+modulate+conv+demod+lrelu ------
// grid 2048 (batch), block 256. LDS-staged xup in two 64-channel halves,
// [64][17][18] f32: row 16 = zeros (handles dy pad), cols 0/17 = zeros (dx pad).
__global__ __launch_bounds__(256) void k_l2(const __half* __restrict__ x1,
    const float* __restrict__ s2, const float* __restrict__ d2g,
    const float* __restrict__ w2c, const float* __restrict__ c2b,
    float* __restrict__ out) {
  int b = blockIdx.x, t = threadIdx.x;
  __shared__ float xup[64][17][18];
  __shared__ float s2l[128];
  if (t < 128) s2l[t] = s2[b * 128 + t];
  for (int i = t; i < 64 * 18; i += 256) {
    int c = i / 18, x = i - c * 18;
    xup[c][16][x] = 0.f;
  }
  for (int i = t; i < 64 * 32; i += 256) {
    int c = i >> 5, r = (i >> 1) & 15, s = i & 1;
    xup[c][r][s * 17] = 0.f;
  }
  __syncthreads();

  int o0 = (t & 7) * 8;                    // 8 output channels per thread
  int g = t >> 3, row = g >> 1, colb = (g & 1) * 8;  // 8 pixels (half row)
  float acc[8][8] = {};                    // [o][px]

  for (int ch = 0; ch < 2; ++ch) {
    // build upsampled, modulated activations for this channel half
    for (int i = t; i < 64 * 256; i += 256) {
      int c = i >> 8, q = i & 255;
      int qy = q >> 4, qx = q & 15;
      int y0, y1, x0, x1i; float wy0, wy1, wx0, wx1;
      up_wi(qy, 8, y0, y1, wy0, wy1);
      up_wi(qx, 8, x0, x1i, wx0, wx1);
      int cg = ch * 64 + c;
      const __half* xp = x1 + (b * 128 + cg) * 64;
      float v00 = __half2float(xp[y0 * 8 + x0]);
      float v01 = __half2float(xp[y0 * 8 + x1i]);
      float v10 = __half2float(xp[y1 * 8 + x0]);
      float v11 = __half2float(xp[y1 * 8 + x1i]);
      float v = wy0 * (wx0 * v00 + wx1 * v01) + wy1 * (wx0 * v10 + wx1 * v11);
      xup[c][qy][qx + 1] = v * s2l[cg];
    }
    __syncthreads();
    for (int c = 0; c < 64; ++c) {
      float xv[3][10];
#pragma unroll
      for (int dy = 0; dy < 3; ++dy) {
        int r = row + dy - 1;
        const float* rp = ((unsigned)r < 16u) ? &xup[c][r][colb] : &xup[c][16][colb];
#pragma unroll
        for (int dx = 0; dx < 10; ++dx) xv[dy][dx] = rp[dx];
      }
      const float* wbase = w2c + (o0 * 128 + ch * 64 + c) * 9;
#pragma unroll
      for (int oj = 0; oj < 8; ++oj) {
        const float* wp = wbase + oj * (128 * 9);
        float w00 = wp[0], w01 = wp[1], w02 = wp[2];
        float w10 = wp[3], w11 = wp[4], w12 = wp[5];
        float w20 = wp[6], w21 = wp[7], w22 = wp[8];
#pragma unroll
        for (int px = 0; px < 8; ++px) {
          acc[oj][px] += w00 * xv[0][px] + w01 * xv[0][px + 1] + w02 * xv[0][px + 2]
                       + w10 * xv[1][px] + w11 * xv[1][px + 1] + w12 * xv[1][px + 2]
                       + w20 * xv[2][px] + w21 * xv[2][px + 1] + w22 * xv[2][px + 2];
        }
      }
    }
    __syncthreads();
  }
#pragma unroll
  for (int oj = 0; oj < 8; ++oj) {
    int o = o0 + oj;
    float dm = d2g[b * 64 + o], bias = c2b[o];
    float* op = out + (b * 64 + o) * 256 + row * 16 + colb;
#pragma unroll
    for (int px = 0; px < 8; ++px) {
      float v = acc[oj][px] * dm + bias;
      op[px] = (v >= 0.f) ? v : 0.2f * v;
    }
  }
}

extern "C" void kernel_launch(void* const* d_in, const int* in_sizes, int n_in,
                              void* d_out, int out_size, void* d_ws, size_t ws_size,
                              hipStream_t stream) {
  const float* w    = (const float*)d_in[0];
  const float* ic   = (const float*)d_in[1];
  const float* w0c  = (const float*)d_in[2];
  const float* b0   = (const float*)d_in[3];
  const float* a1w  = (const float*)d_in[4];
  const float* a1b  = (const float*)d_in[5];
  const float* w1c  = (const float*)d_in[6];
  const float* c1b  = (const float*)d_in[7];
  const float* a2w  = (const float*)d_in[8];
  const float* a2b  = (const float*)d_in[9];
  const float* w2c  = (const float*)d_in[10];
  const float* c2b  = (const float*)d_in[11];
  float* out = (float*)d_out;
  char* ws = (char*)d_ws;

  float*  x0u = (float*)(ws + WS_X0U);
  float*  G   = (float*)(ws + WS_G);
  float*  w2a = (float*)(ws + WS_W2A);
  float*  w2b = (float*)(ws + WS_W2B);
  float*  s1  = (float*)(ws + WS_S1);
  float*  s2  = (float*)(ws + WS_S2);
  float*  d1  = (float*)(ws + WS_D1);
  float*  d2  = (float*)(ws + WS_D2);
  __half* x1  = (__half*)(ws + WS_X1);

  k_init <<<256, 64, 0, stream>>>(ic, w0c, b0, x0u);
  k_prep <<<128, 256, 0, stream>>>(w1c, w2c, x0u, G, w2a, w2b);
  k_style<<<128, 256, 0, stream>>>(w, a1w, a1b, a2w, a2b, w2a, w2b, s1, s2, d1, d2);
  dim3 g1(32, 32);
  k_l1   <<<g1, 256, 0, stream>>>(s1, G, d1, c1b, x1);
  k_l2   <<<2048, 256, 0, stream>>>(x1, s2, d2, w2c, c2b, out);
}

// Round 2
// 661.912 us; speedup vs baseline: 4.7414x; 4.7414x over previous
//
#include <hip/hip_runtime.h>
#include <hip/hip_fp16.h>

typedef _Float16 f16x8 __attribute__((ext_vector_type(8)));
typedef float f32x4 __attribute__((ext_vector_type(4)));

// ---------------- workspace layout (bytes) ----------------
#define WS_X0U   0            // 256*64*4   = 65536      x0u f32 [c][64]
#define WS_GHP   65536        // 8192*256*2 = 4194304    Ghp f16 frag-packed [n][c]
#define WS_W2P   4259840      // 9*4*4*64*8*2 = 147456   w2 f16 frag-packed
#define WS_W2A   4407296      // 128*256*4  = 131072     sum_k W1^2 [o][c]
#define WS_W2B   4538368      // 64*128*4   = 32768      sum_k W2^2 [o][c]
#define WS_S1P   4571136      // 2048*256*2 = 1048576    style1 f16 frag-packed
#define WS_S2    5619712      // 2048*128*4 = 1048576    style2 f32
#define WS_D1    6668288      // 2048*128*4 = 1048576    demod1
#define WS_D2    7716864      // 2048*64*4  = 524288     demod2
#define WS_X1T   8241152      // 2048*64*128*2 = 33554432  x1t f16 [b][p][o]

// bilinear x2, half-pixel centers
__device__ __forceinline__ void up_wi(int j, int S, int& i0, int& i1,
                                      float& w0, float& w1) {
  int m = j >> 1;
  if (j & 1) { i0 = m; i1 = (m + 1 < S) ? m + 1 : S - 1; w0 = 0.75f; w1 = 0.25f; }
  else       { i0 = (m - 1 >= 0) ? m - 1 : 0; i1 = m;     w0 = 0.25f; w1 = 0.75f; }
}

// ---------------- K0: init conv + lrelu + upsample 4->8 ----------------
__global__ __launch_bounds__(64) void k_init(const float* __restrict__ ic,
    const float* __restrict__ w0c, const float* __restrict__ b0,
    float* __restrict__ x0u) {
  int o = blockIdx.x, t = threadIdx.x;
  __shared__ float part[4][16];
  __shared__ float x4[16];
  int pix = t & 15, cg = t >> 4;
  int py = pix >> 2, px = pix & 3;
  float acc = 0.f;
  for (int c = cg * 128; c < cg * 128 + 128; ++c) {
    const float* wp = w0c + (o * 512 + c) * 9;
    const float* xp = ic + c * 16;
#pragma unroll
    for (int dy = 0; dy < 3; ++dy) {
      int iy = py + dy - 1;
      if ((unsigned)iy >= 4u) continue;
#pragma unroll
      for (int dx = 0; dx < 3; ++dx) {
        int ix = px + dx - 1;
        if ((unsigned)ix >= 4u) continue;
        acc += wp[dy * 3 + dx] * xp[iy * 4 + ix];
      }
    }
  }
  part[cg][pix] = acc;
  __syncthreads();
  if (t < 16) {
    float v = part[0][t] + part[1][t] + part[2][t] + part[3][t] + b0[o];
    x4[t] = (v >= 0.f) ? v : 0.2f * v;
  }
  __syncthreads();
  int oy = t >> 3, ox = t & 7;
  int y0, y1, xx0, xx1; float wy0, wy1, wx0, wx1;
  up_wi(oy, 4, y0, y1, wy0, wy1);
  up_wi(ox, 4, xx0, xx1, wx0, wx1);
  float v = wy0 * (wx0 * x4[y0 * 4 + xx0] + wx1 * x4[y0 * 4 + xx1])
          + wy1 * (wx0 * x4[y1 * 4 + xx0] + wx1 * x4[y1 * 4 + xx1]);
  x0u[o * 64 + t] = v;
}

// ---------------- K_prep: Ghp[n=p*128+o][c] frag-packed f16 --------------
// grid 128 (o), block 256 (c)
__global__ __launch_bounds__(256) void k_prep(const float* __restrict__ w1c,
    const float* __restrict__ x0u, _Float16* __restrict__ Ghp) {
  int o = blockIdx.x, t = threadIdx.x;
  __shared__ _Float16 x0l[256][66];
  for (int i = t; i < 256 * 64; i += 256) {
    int c = i >> 6, p = i & 63;
    x0l[c][p] = (_Float16)x0u[i];
  }
  __syncthreads();
  int c = t;
  float wr9[9];
#pragma unroll
  for (int k = 0; k < 9; ++k) wr9[k] = w1c[(o * 256 + c) * 9 + k];
  int cpart = ((((c >> 3) & 3) * 16 + (o & 15)) * 8) + (c & 7);
  int cq = c >> 5, oq = o >> 4;
  for (int p = 0; p < 64; ++p) {
    int py = p >> 3, px = p & 7;
    float acc = 0.f;
#pragma unroll
    for (int dy = 0; dy < 3; ++dy) {
      int iy = py + dy - 1;
      if ((unsigned)iy >= 8u) continue;
#pragma unroll
      for (int dx = 0; dx < 3; ++dx) {
        int ix = px + dx - 1;
        if ((unsigned)ix >= 8u) continue;
        acc += wr9[dy * 3 + dx] * (float)x0l[c][iy * 8 + ix];
      }
    }
    // flat = ((n>>4)*8 + c>>5)*512 + cpart,  n = p*128+o  -> n>>4 = p*8+oq
    Ghp[((p * 8 + oq) * 8 + cq) * 512 + cpart] = (_Float16)acc;
  }
}

// ---------------- K_misc: w2p frag-packed f16, w2a, w2b ------------------
// grid 448, block 256
__global__ __launch_bounds__(256) void k_misc(const float* __restrict__ w1c,
    const float* __restrict__ w2c, _Float16* __restrict__ w2p,
    float* __restrict__ w2a, float* __restrict__ w2b) {
  int idx = blockIdx.x * 256 + threadIdx.x;
  if (idx < 73728) {
    int tap = idx / 8192, r = idx & 8191;
    int kg = r >> 11, mf = (r >> 9) & 3, l = (r >> 3) & 63, j = r & 7;
    int o = mf * 16 + (l & 15);
    int c = kg * 32 + (l >> 4) * 8 + j;
    w2p[idx] = (_Float16)w2c[(o * 128 + c) * 9 + tap];
  } else if (idx < 73728 + 32768) {
    int i = idx - 73728;
    const float* wp = w1c + i * 9;
    float s = 0.f;
#pragma unroll
    for (int k = 0; k < 9; ++k) s += wp[k] * wp[k];
    w2a[i] = s;
  } else if (idx < 73728 + 32768 + 8192) {
    int i = idx - 73728 - 32768;
    const float* wp = w2c + i * 9;
    float s = 0.f;
#pragma unroll
    for (int k = 0; k < 9; ++k) s += wp[k] * wp[k];
    w2b[i] = s;
  }
}

// ---------------- K_style: styles + demods ------------------------------
// grid 128, block 256 (16 batches/block)
__global__ __launch_bounds__(256) void k_style(const float* __restrict__ w,
    const float* __restrict__ a1w, const float* __restrict__ a1b,
    const float* __restrict__ a2w, const float* __restrict__ a2b,
    const float* __restrict__ w2a, const float* __restrict__ w2b,
    _Float16* __restrict__ s1p, float* __restrict__ s2,
    float* __restrict__ d1, float* __restrict__ d2) {
  int b0 = blockIdx.x * 16, t = threadIdx.x;
  __shared__ float wl[16][512];
  __shared__ float sl[16][384];
  for (int i = t; i < 16 * 512; i += 256) {
    int bi = i >> 9, k = i & 511;
    wl[bi][k] = w[(b0 + bi) * 512 + k];
  }
  __syncthreads();
  int bi = t >> 4, fg = t & 15;
  int b = b0 + bi;
  for (int j = 0; j < 24; ++j) {
    int f = fg + 16 * j;
    const float* ap; float bias;
    if (f < 256) { ap = a1w + f * 512; bias = a1b[f]; }
    else         { ap = a2w + (f - 256) * 512; bias = a2b[f - 256]; }
    float acc = bias;
    for (int k = 0; k < 512; k += 4) {
      float4 wv = *(const float4*)&wl[bi][k];
      float4 av = *(const float4*)&ap[k];
      acc += wv.x * av.x + wv.y * av.y + wv.z * av.z + wv.w * av.w;
    }
    sl[bi][f] = acc;
    if (f < 256) {
      int flat = (((b >> 4) * 8 + (f >> 5)) * 64 + ((f >> 3) & 3) * 16 + (b & 15)) * 8 + (f & 7);
      s1p[flat] = (_Float16)acc;
    } else {
      s2[b * 128 + (f - 256)] = acc;
    }
  }
  __syncthreads();
  for (int j = 0; j < 8; ++j) {
    int oo = fg + 16 * j;
    float acc = 1e-8f;
    const float* w2pp = w2a + oo * 256;
    for (int c = 0; c < 256; ++c) { float s = sl[bi][c]; acc += s * s * w2pp[c]; }
    d1[b * 128 + oo] = rsqrtf(acc);
  }
  for (int j = 0; j < 4; ++j) {
    int oo = fg + 16 * j;
    float acc = 1e-8f;
    const float* w2pp = w2b + oo * 128;
    for (int c = 0; c < 128; ++c) { float s = sl[bi][256 + c]; acc += s * s * w2pp[c]; }
    d2[b * 64 + oo] = rsqrtf(acc);
  }
}

// ---------------- K_l1: MFMA GEMM  M=2048(b) N=8192(p*128+o) K=256 -------
// grid (64,16), block 256 (4 waves, 2x2), tile 128x128
__global__ __launch_bounds__(256) void k_l1(const _Float16* __restrict__ s1p,
    const _Float16* __restrict__ Ghp, const float* __restrict__ d1,
    const float* __restrict__ c1b, __half* __restrict__ x1t) {
  int t = threadIdx.x, lane = t & 63, w = t >> 6;
  int wr = w >> 1, wc = w & 1;
  int bq0 = blockIdx.y * 8 + wr * 4;
  int nq0 = blockIdx.x * 8 + wc * 4;
  f32x4 acc[4][4] = {};
  for (int kg = 0; kg < 8; ++kg) {
    f16x8 af[4], bf[4];
#pragma unroll
    for (int mf = 0; mf < 4; ++mf)
      af[mf] = *(const f16x8*)(s1p + (((bq0 + mf) * 8 + kg) * 64 + lane) * 8);
#pragma unroll
    for (int nf = 0; nf < 4; ++nf)
      bf[nf] = *(const f16x8*)(Ghp + (((nq0 + nf) * 8 + kg) * 64 + lane) * 8);
#pragma unroll
    for (int mf = 0; mf < 4; ++mf)
#pragma unroll
      for (int nf = 0; nf < 4; ++nf)
        acc[mf][nf] = __builtin_amdgcn_mfma_f32_16x16x32_f16(af[mf], bf[nf], acc[mf][nf], 0, 0, 0);
  }
  int nc = lane & 15, r4 = lane >> 4;
#pragma unroll
  for (int mf = 0; mf < 4; ++mf) {
#pragma unroll
    for (int r = 0; r < 4; ++r) {
      int b = (bq0 + mf) * 16 + r4 * 4 + r;
#pragma unroll
      for (int nf = 0; nf < 4; ++nf) {
        int n = (nq0 + nf) * 16 + nc;
        int o = n & 127, p = n >> 7;
        float v = acc[mf][nf][r] * d1[b * 128 + o] + c1b[o];
        v = (v >= 0.f) ? v : 0.2f * v;
        x1t[(b * 64 + p) * 128 + o] = (__half)v;
      }
    }
  }
}

// ---------------- K_l2: per-batch upsample+modulate+conv (MFMA) ----------
// grid 2048 (batch), block 256 (4 waves). 9 tap-GEMMs M=64(o) N=256(px) K=128(c)
__global__ __launch_bounds__(256) void k_l2(const __half* __restrict__ x1t,
    const float* __restrict__ s2, const float* __restrict__ d2g,
    const _Float16* __restrict__ w2p, const float* __restrict__ c2b,
    float* __restrict__ out) {
  int b = blockIdx.x, t = threadIdx.x;
  int lane = t & 63, w = t >> 6;
  __shared__ unsigned short xup[324 * 64];   // [pix 18x18][64 ch] swizzled 16B granules
  __shared__ unsigned short x1l[64 * 128];   // [q 8x8][128 ch] swizzled
  __shared__ float s2l[128];
  if (t < 128) s2l[t] = s2[b * 128 + t];
  // stage x1t[b] -> LDS (swizzled granules)
  {
    const __half* src = x1t + b * 8192;
    for (int idx = t; idx < 1024; idx += 256) {
      int q = idx >> 4, gc = idx & 15;
      f16x8 v = *(const f16x8*)(src + q * 128 + gc * 8);
      int gs = (gc & 8) | ((gc ^ q) & 7);
      *(f16x8*)&x1l[q * 128 + gs * 8] = v;
    }
  }
  // zero border ring of xup (68 pixels x 8 granules) — once, reused by both halves
  {
    f16x8 z = {};
    for (int idx = t; idx < 68 * 8; idx += 256) {
      int bp = idx >> 3, g = idx & 7;
      int pix;
      if (bp < 18) pix = bp;
      else if (bp < 36) pix = 306 + (bp - 18);
      else { int r = (bp - 36) >> 1; pix = (r + 1) * 18 + ((bp - 36) & 1) * 17; }
      *(f16x8*)&xup[pix * 64 + g * 8] = z;
    }
  }
  // per-thread upsample geometry: one fine pixel per thread
  int fy = t >> 4, fx = t & 15;
  int y0, y1, x0, x1i; float wy0, wy1, wx0, wx1;
  up_wi(fy, 8, y0, y1, wy0, wy1);
  up_wi(fx, 8, x0, x1i, wx0, wx1);
  int pixpad = (fy + 1) * 18 + (fx + 1);
  int q00 = y0 * 8 + x0, q01 = y0 * 8 + x1i, q10 = y1 * 8 + x0, q11 = y1 * 8 + x1i;
  __syncthreads();

  f32x4 acc[4][4] = {};   // [mf(o)][nf(row)]
  for (int h = 0; h < 2; ++h) {
    if (h) __syncthreads();
    // build upsampled+modulated interior for channels [h*64, h*64+64)
#pragma unroll
    for (int i = 0; i < 8; ++i) {
      int gc = h * 8 + i;
      f16x8 va = *(const f16x8*)&x1l[q00 * 128 + ((gc & 8) | ((gc ^ q00) & 7)) * 8];
      f16x8 vb = *(const f16x8*)&x1l[q01 * 128 + ((gc & 8) | ((gc ^ q01) & 7)) * 8];
      f16x8 vc = *(const f16x8*)&x1l[q10 * 128 + ((gc & 8) | ((gc ^ q10) & 7)) * 8];
      f16x8 vd = *(const f16x8*)&x1l[q11 * 128 + ((gc & 8) | ((gc ^ q11) & 7)) * 8];
      const float* sp = &s2l[h * 64 + i * 8];
      f16x8 o8;
#pragma unroll
      for (int j = 0; j < 8; ++j) {
        float v = wy0 * (wx0 * (float)va[j] + wx1 * (float)vb[j])
                + wy1 * (wx0 * (float)vc[j] + wx1 * (float)vd[j]);
        o8[j] = (_Float16)(v * sp[j]);
      }
      *(f16x8*)&xup[pixpad * 64 + ((i ^ (pixpad & 7)) * 8)] = o8;
    }
    __syncthreads();
    // MFMA over this channel half: kk = 32-ch chunk, 9 taps
    for (int kk = 0; kk < 2; ++kk) {
      int kg = h * 2 + kk;
#pragma unroll
      for (int tap = 0; tap < 9; ++tap) {
        int dy = tap / 3, dx = tap - dy * 3;
        f16x8 af[4];
#pragma unroll
        for (int mf = 0; mf < 4; ++mf)
          af[mf] = *(const f16x8*)(w2p + (((tap * 4 + kg) * 4 + mf) * 64 + lane) * 8);
        f16x8 bf[4];
        int g = kk * 4 + (lane >> 4);
#pragma unroll
        for (int nf = 0; nf < 4; ++nf) {
          int pix = (w * 4 + nf + dy) * 18 + (lane & 15) + dx;
          bf[nf] = *(const f16x8*)&xup[pix * 64 + ((g ^ (pix & 7)) * 8)];
        }
#pragma unroll
        for (int mf = 0; mf < 4; ++mf)
#pragma unroll
          for (int nf = 0; nf < 4; ++nf)
            acc[mf][nf] = __builtin_amdgcn_mfma_f32_16x16x32_f16(af[mf], bf[nf], acc[mf][nf], 0, 0, 0);
      }
    }
  }
  // epilogue: demod + bias + lrelu, f32 out
  int px = lane & 15, r4 = lane >> 4;
#pragma unroll
  for (int mf = 0; mf < 4; ++mf) {
#pragma unroll
    for (int r = 0; r < 4; ++r) {
      int o = mf * 16 + r4 * 4 + r;
      float dm = d2g[b * 64 + o], bias = c2b[o];
#pragma unroll
      for (int nf = 0; nf < 4; ++nf) {
        int py = w * 4 + nf;
        float v = acc[mf][nf][r] * dm + bias;
        v = (v >= 0.f) ? v : 0.2f * v;
        out[(b * 64 + o) * 256 + py * 16 + px] = v;
      }
    }
  }
}

extern "C" void kernel_launch(void* const* d_in, const int* in_sizes, int n_in,
                              void* d_out, int out_size, void* d_ws, size_t ws_size,
                              hipStream_t stream) {
  const float* w    = (const float*)d_in[0];
  const float* ic   = (const float*)d_in[1];
  const float* w0c  = (const float*)d_in[2];
  const float* b0   = (const float*)d_in[3];
  const float* a1w  = (const float*)d_in[4];
  const float* a1b  = (const float*)d_in[5];
  const float* w1c  = (const float*)d_in[6];
  const float* c1b  = (const float*)d_in[7];
  const float* a2w  = (const float*)d_in[8];
  const float* a2b  = (const float*)d_in[9];
  const float* w2c  = (const float*)d_in[10];
  const float* c2b  = (const float*)d_in[11];
  float* out = (float*)d_out;
  char* ws = (char*)d_ws;

  float*    x0u = (float*)(ws + WS_X0U);
  _Float16* Ghp = (_Float16*)(ws + WS_GHP);
  _Float16* w2p = (_Float16*)(ws + WS_W2P);
  float*    w2a = (float*)(ws + WS_W2A);
  float*    w2b = (float*)(ws + WS_W2B);
  _Float16* s1p = (_Float16*)(ws + WS_S1P);
  float*    s2  = (float*)(ws + WS_S2);
  float*    d1  = (float*)(ws + WS_D1);
  float*    d2  = (float*)(ws + WS_D2);
  __half*   x1t = (__half*)(ws + WS_X1T);

  k_init <<<256, 64, 0, stream>>>(ic, w0c, b0, x0u);
  k_prep <<<128, 256, 0, stream>>>(w1c, x0u, Ghp);
  k_misc <<<448, 256, 0, stream>>>(w1c, w2c, w2p, w2a, w2b);
  k_style<<<128, 256, 0, stream>>>(w, a1w, a1b, a2w, a2b, w2a, w2b, s1p, s2, d1, d2);
  dim3 g1(64, 16);
  k_l1   <<<g1, 256, 0, stream>>>(s1p, Ghp, d1, c1b, x1t);
  k_l2   <<<2048, 256, 0, stream>>>(x1t, s2, d2, w2p, c2b, out);
}

// Round 3
// 317.074 us; speedup vs baseline: 9.8981x; 2.0876x over previous
//
#include <hip/hip_runtime.h>
#include <hip/hip_fp16.h>

typedef _Float16 f16x8 __attribute__((ext_vector_type(8)));
typedef float f32x4 __attribute__((ext_vector_type(4)));

// ---------------- workspace layout (bytes) ----------------
#define WS_X0U   0            // 256*64*4   = 65536      x0u f32 [c][64]
#define WS_GHP   65536        // 8192*256*2 = 4194304    Ghp f16 frag-packed [n][c]
#define WS_W2P   4259840      // 9*4*4*64*8*2 = 147456   w2 f16 frag-packed
#define WS_AFT   4407296      // 512*384*4  = 786432     affT[k][f]
#define WS_W2T   5193728      // 384*192*4  = 294912     W2catT[k][o]
#define WS_S     5488640      // 2048*384*4 = 3145728    styles f32 [b][f]
#define WS_S1P   8634368      // 2048*256*2 = 1048576    style1 f16 frag-packed
#define WS_S2    9682944      // 2048*128*4 = 1048576    style2 f32
#define WS_D1    10731520     // 2048*128*4 = 1048576    demod1
#define WS_D2    11780096     // 2048*64*4  = 524288     demod2
#define WS_X1T   12304384     // 2048*64*128*2 = 33554432  x1t f16 [b][p][o]

// bilinear x2, half-pixel centers
__device__ __forceinline__ void up_wi(int j, int S, int& i0, int& i1,
                                      float& w0, float& w1) {
  int m = j >> 1;
  if (j & 1) { i0 = m; i1 = (m + 1 < S) ? m + 1 : S - 1; w0 = 0.75f; w1 = 0.25f; }
  else       { i0 = (m - 1 >= 0) ? m - 1 : 0; i1 = m;     w0 = 0.25f; w1 = 0.75f; }
}

// ---------------- K0: init conv + lrelu + upsample 4->8 ----------------
__global__ __launch_bounds__(64) void k_init(const float* __restrict__ ic,
    const float* __restrict__ w0c, const float* __restrict__ b0,
    float* __restrict__ x0u) {
  int o = blockIdx.x, t = threadIdx.x;
  __shared__ float part[4][16];
  __shared__ float x4[16];
  int pix = t & 15, cg = t >> 4;
  int py = pix >> 2, px = pix & 3;
  float acc = 0.f;
  for (int c = cg * 128; c < cg * 128 + 128; ++c) {
    const float* wp = w0c + (o * 512 + c) * 9;
    const float* xp = ic + c * 16;
#pragma unroll
    for (int dy = 0; dy < 3; ++dy) {
      int iy = py + dy - 1;
      if ((unsigned)iy >= 4u) continue;
#pragma unroll
      for (int dx = 0; dx < 3; ++dx) {
        int ix = px + dx - 1;
        if ((unsigned)ix >= 4u) continue;
        acc += wp[dy * 3 + dx] * xp[iy * 4 + ix];
      }
    }
  }
  part[cg][pix] = acc;
  __syncthreads();
  if (t < 16) {
    float v = part[0][t] + part[1][t] + part[2][t] + part[3][t] + b0[o];
    x4[t] = (v >= 0.f) ? v : 0.2f * v;
  }
  __syncthreads();
  int oy = t >> 3, ox = t & 7;
  int y0, y1, xx0, xx1; float wy0, wy1, wx0, wx1;
  up_wi(oy, 4, y0, y1, wy0, wy1);
  up_wi(ox, 4, xx0, xx1, wx0, wx1);
  float v = wy0 * (wx0 * x4[y0 * 4 + xx0] + wx1 * x4[y0 * 4 + xx1])
          + wy1 * (wx0 * x4[y1 * 4 + xx0] + wx1 * x4[y1 * 4 + xx1]);
  x0u[o * 64 + t] = v;
}

// ---------------- K_prep: Ghp[n=p*128+o][c] frag-packed f16 --------------
__global__ __launch_bounds__(256) void k_prep(const float* __restrict__ w1c,
    const float* __restrict__ x0u, _Float16* __restrict__ Ghp) {
  int o = blockIdx.x, t = threadIdx.x;
  __shared__ _Float16 x0l[256][66];
  for (int i = t; i < 256 * 64; i += 256) {
    int c = i >> 6, p = i & 63;
    x0l[c][p] = (_Float16)x0u[i];
  }
  __syncthreads();
  int c = t;
  float wr9[9];
#pragma unroll
  for (int k = 0; k < 9; ++k) wr9[k] = w1c[(o * 256 + c) * 9 + k];
  int cpart = ((((c >> 3) & 3) * 16 + (o & 15)) * 8) + (c & 7);
  int cq = c >> 5, oq = o >> 4;
  for (int p = 0; p < 64; ++p) {
    int py = p >> 3, px = p & 7;
    float acc = 0.f;
#pragma unroll
    for (int dy = 0; dy < 3; ++dy) {
      int iy = py + dy - 1;
      if ((unsigned)iy >= 8u) continue;
#pragma unroll
      for (int dx = 0; dx < 3; ++dx) {
        int ix = px + dx - 1;
        if ((unsigned)ix >= 8u) continue;
        acc += wr9[dy * 3 + dx] * (float)x0l[c][iy * 8 + ix];
      }
    }
    Ghp[((p * 8 + oq) * 8 + cq) * 512 + cpart] = (_Float16)acc;
  }
}

// ---------------- K_misc: w2p frag-packed f16, affT, W2catT --------------
// grid 1344, block 256
__global__ __launch_bounds__(256) void k_misc(const float* __restrict__ w1c,
    const float* __restrict__ w2c, const float* __restrict__ a1w,
    const float* __restrict__ a2w, _Float16* __restrict__ w2p,
    float* __restrict__ affT, float* __restrict__ W2T) {
  int idx = blockIdx.x * 256 + threadIdx.x;
  if (idx < 73728) {
    int tap = idx / 8192, r = idx & 8191;
    int kg = r >> 11, mf = (r >> 9) & 3, l = (r >> 3) & 63, j = r & 7;
    int o = mf * 16 + (l & 15);
    int c = kg * 32 + (l >> 4) * 8 + j;
    w2p[idx] = (_Float16)w2c[(o * 128 + c) * 9 + tap];
  } else if (idx < 73728 + 196608) {
    int i = idx - 73728;           // i = k*384 + f
    int k = i / 384, f = i - k * 384;
    affT[i] = (f < 256) ? a1w[f * 512 + k] : a2w[(f - 256) * 512 + k];
  } else if (idx < 73728 + 196608 + 73728) {
    int i = idx - 73728 - 196608;  // i = k*192 + o
    int k = i / 192, o = i - k * 192;
    float v = 0.f;
    const float* wp = nullptr;
    if (o < 128 && k < 256)        wp = w1c + (o * 256 + k) * 9;
    else if (o >= 128 && k >= 256) wp = w2c + ((o - 128) * 128 + (k - 256)) * 9;
    if (wp) {
#pragma unroll
      for (int q = 0; q < 9; ++q) v += wp[q] * wp[q];
    }
    W2T[i] = v;
  }
}

// ---------------- K_sty: styles GEMM  s[2048][384] = w @ affT (+bias) ----
// tile 64(M=b) x 48(N=f), 128 threads, reg 4x6, grid (8, 32)
__global__ __launch_bounds__(128) void k_sty(const float* __restrict__ w,
    const float* __restrict__ affT, const float* __restrict__ a1b,
    const float* __restrict__ a2b, float* __restrict__ s,
    _Float16* __restrict__ s1p, float* __restrict__ s2) {
  int n0 = blockIdx.x * 48, b0 = blockIdx.y * 64;
  int t = threadIdx.x;
  __shared__ float As[32][68];
  __shared__ float Bs[32][52];
  float acc[4][6] = {};
  int rb = t >> 3, cb = t & 7;
  int arow = t >> 1, akg = (t & 1) * 16;
  int bk = t >> 2, bc0 = (t & 3) * 12;
  for (int kc = 0; kc < 512; kc += 32) {
    {
      const float* src = w + (b0 + arow) * 512 + kc + akg;
#pragma unroll
      for (int q = 0; q < 4; ++q) {
        float4 v = *(const float4*)(src + q * 4);
        As[akg + q * 4 + 0][arow] = v.x;
        As[akg + q * 4 + 1][arow] = v.y;
        As[akg + q * 4 + 2][arow] = v.z;
        As[akg + q * 4 + 3][arow] = v.w;
      }
    }
    {
      const float* src = affT + (kc + bk) * 384 + n0 + bc0;
      float* dst = &Bs[bk][bc0];
      *(float4*)dst       = *(const float4*)src;
      *(float4*)(dst + 4) = *(const float4*)(src + 4);
      *(float4*)(dst + 8) = *(const float4*)(src + 8);
    }
    __syncthreads();
#pragma unroll
    for (int k = 0; k < 32; ++k) {
      float4 a4 = *(const float4*)&As[k][rb * 4];
      float a[4] = {a4.x, a4.y, a4.z, a4.w};
      float b6[6];
      *(float2*)&b6[0] = *(const float2*)&Bs[k][cb * 6];
      *(float2*)&b6[2] = *(const float2*)&Bs[k][cb * 6 + 2];
      *(float2*)&b6[4] = *(const float2*)&Bs[k][cb * 6 + 4];
#pragma unroll
      for (int i = 0; i < 4; ++i)
#pragma unroll
        for (int j = 0; j < 6; ++j) acc[i][j] += a[i] * b6[j];
    }
    __syncthreads();
  }
#pragma unroll
  for (int j = 0; j < 6; ++j) {
    int f = n0 + cb * 6 + j;
    float bias = (f < 256) ? a1b[f] : a2b[f - 256];
#pragma unroll
    for (int i = 0; i < 4; ++i) {
      int b = b0 + rb * 4 + i;
      float v = acc[i][j] + bias;
      s[b * 384 + f] = v;
      if (f < 256) {
        int flat = (((b >> 4) * 8 + (f >> 5)) * 64 + ((f >> 3) & 3) * 16 + (b & 15)) * 8 + (f & 7);
        s1p[flat] = (_Float16)v;
      } else {
        s2[b * 128 + (f - 256)] = v;
      }
    }
  }
}

// ---------------- K_dmd: demods GEMM  rsqrt(s^2 @ W2T + eps) -------------
// tile 64(M=b) x 64(N=o), 128 threads, reg 4x8, grid (3, 32)
// N-tiles 0,1 (o<128): K in [0,256); N-tile 2 (o>=128): K in [256,384)
__global__ __launch_bounds__(128) void k_dmd(const float* __restrict__ s,
    const float* __restrict__ W2T, float* __restrict__ d1,
    float* __restrict__ d2) {
  int n0 = blockIdx.x * 64, b0 = blockIdx.y * 64;
  int t = threadIdx.x;
  __shared__ float As[32][68];
  __shared__ float Bs[32][68];
  float acc[4][8] = {};
  int rb = t >> 3, cb = t & 7;
  int arow = t >> 1, akg = (t & 1) * 16;
  int bk = t >> 2, bc0 = (t & 3) * 16;
  int k_beg = (n0 >= 128) ? 256 : 0;
  int k_end = (n0 >= 128) ? 384 : 256;
  for (int kc = k_beg; kc < k_end; kc += 32) {
    {
      const float* src = s + (b0 + arow) * 384 + kc + akg;
#pragma unroll
      for (int q = 0; q < 4; ++q) {
        float4 v = *(const float4*)(src + q * 4);
        As[akg + q * 4 + 0][arow] = v.x * v.x;
        As[akg + q * 4 + 1][arow] = v.y * v.y;
        As[akg + q * 4 + 2][arow] = v.z * v.z;
        As[akg + q * 4 + 3][arow] = v.w * v.w;
      }
    }
    {
      const float* src = W2T + (kc + bk) * 192 + n0 + bc0;
      float* dst = &Bs[bk][bc0];
#pragma unroll
      for (int q = 0; q < 4; ++q)
        *(float4*)(dst + q * 4) = *(const float4*)(src + q * 4);
    }
    __syncthreads();
#pragma unroll
    for (int k = 0; k < 32; ++k) {
      float4 a4 = *(const float4*)&As[k][rb * 4];
      float a[4] = {a4.x, a4.y, a4.z, a4.w};
      float b8[8];
      *(float4*)&b8[0] = *(const float4*)&Bs[k][cb * 8];
      *(float4*)&b8[4] = *(const float4*)&Bs[k][cb * 8 + 4];
#pragma unroll
      for (int i = 0; i < 4; ++i)
#pragma unroll
        for (int j = 0; j < 8; ++j) acc[i][j] += a[i] * b8[j];
    }
    __syncthreads();
  }
#pragma unroll
  for (int j = 0; j < 8; ++j) {
    int o = n0 + cb * 8 + j;
#pragma unroll
    for (int i = 0; i < 4; ++i) {
      int b = b0 + rb * 4 + i;
      float v = rsqrtf(acc[i][j] + 1e-8f);
      if (o < 128) d1[b * 128 + o] = v;
      else         d2[b * 64 + (o - 128)] = v;
    }
  }
}

// ---------------- K_l1: MFMA GEMM  M=2048(b) N=8192(p*128+o) K=256 -------
__global__ __launch_bounds__(256) void k_l1(const _Float16* __restrict__ s1p,
    const _Float16* __restrict__ Ghp, const float* __restrict__ d1,
    const float* __restrict__ c1b, __half* __restrict__ x1t) {
  int t = threadIdx.x, lane = t & 63, w = t >> 6;
  int wr = w >> 1, wc = w & 1;
  int bq0 = blockIdx.y * 8 + wr * 4;
  int nq0 = blockIdx.x * 8 + wc * 4;
  f32x4 acc[4][4] = {};
  for (int kg = 0; kg < 8; ++kg) {
    f16x8 af[4], bf[4];
#pragma unroll
    for (int mf = 0; mf < 4; ++mf)
      af[mf] = *(const f16x8*)(s1p + (((bq0 + mf) * 8 + kg) * 64 + lane) * 8);
#pragma unroll
    for (int nf = 0; nf < 4; ++nf)
      bf[nf] = *(const f16x8*)(Ghp + (((nq0 + nf) * 8 + kg) * 64 + lane) * 8);
#pragma unroll
    for (int mf = 0; mf < 4; ++mf)
#pragma unroll
      for (int nf = 0; nf < 4; ++nf)
        acc[mf][nf] = __builtin_amdgcn_mfma_f32_16x16x32_f16(af[mf], bf[nf], acc[mf][nf], 0, 0, 0);
  }
  int nc = lane & 15, r4 = lane >> 4;
#pragma unroll
  for (int mf = 0; mf < 4; ++mf) {
#pragma unroll
    for (int r = 0; r < 4; ++r) {
      int b = (bq0 + mf) * 16 + r4 * 4 + r;
#pragma unroll
      for (int nf = 0; nf < 4; ++nf) {
        int n = (nq0 + nf) * 16 + nc;
        int o = n & 127, p = n >> 7;
        float v = acc[mf][nf][r] * d1[b * 128 + o] + c1b[o];
        v = (v >= 0.f) ? v : 0.2f * v;
        x1t[(b * 64 + p) * 128 + o] = (__half)v;
      }
    }
  }
}

// ---------------- K_l2: per-batch upsample+modulate+conv (MFMA) ----------
__global__ __launch_bounds__(256) void k_l2(const __half* __restrict__ x1t,
    const float* __restrict__ s2, const float* __restrict__ d2g,
    const _Float16* __restrict__ w2p, const float* __restrict__ c2b,
    float* __restrict__ out) {
  int b = blockIdx.x, t = threadIdx.x;
  int lane = t & 63, w = t >> 6;
  __shared__ unsigned short xup[324 * 64];   // [pix 18x18][64 ch] swizzled 16B granules
  __shared__ unsigned short x1l[64 * 128];   // [q 8x8][128 ch] swizzled
  __shared__ float s2l[128];
  if (t < 128) s2l[t] = s2[b * 128 + t];
  {
    const __half* src = x1t + b * 8192;
    for (int idx = t; idx < 1024; idx += 256) {
      int q = idx >> 4, gc = idx & 15;
      f16x8 v = *(const f16x8*)(src + q * 128 + gc * 8);
      int gs = (gc & 8) | ((gc ^ q) & 7);
      *(f16x8*)&x1l[q * 128 + gs * 8] = v;
    }
  }
  {
    f16x8 z = {};
    for (int idx = t; idx < 68 * 8; idx += 256) {
      int bp = idx >> 3, g = idx & 7;
      int pix;
      if (bp < 18) pix = bp;
      else if (bp < 36) pix = 306 + (bp - 18);
      else { int r = (bp - 36) >> 1; pix = (r + 1) * 18 + ((bp - 36) & 1) * 17; }
      *(f16x8*)&xup[pix * 64 + g * 8] = z;
    }
  }
  int fy = t >> 4, fx = t & 15;
  int y0, y1, x0, x1i; float wy0, wy1, wx0, wx1;
  up_wi(fy, 8, y0, y1, wy0, wy1);
  up_wi(fx, 8, x0, x1i, wx0, wx1);
  int pixpad = (fy + 1) * 18 + (fx + 1);
  int q00 = y0 * 8 + x0, q01 = y0 * 8 + x1i, q10 = y1 * 8 + x0, q11 = y1 * 8 + x1i;
  __syncthreads();

  f32x4 acc[4][4] = {};   // [mf(o)][nf(row)]
  for (int h = 0; h < 2; ++h) {
    if (h) __syncthreads();
#pragma unroll
    for (int i = 0; i < 8; ++i) {
      int gc = h * 8 + i;
      f16x8 va = *(const f16x8*)&x1l[q00 * 128 + ((gc & 8) | ((gc ^ q00) & 7)) * 8];
      f16x8 vb = *(const f16x8*)&x1l[q01 * 128 + ((gc & 8) | ((gc ^ q01) & 7)) * 8];
      f16x8 vc = *(const f16x8*)&x1l[q10 * 128 + ((gc & 8) | ((gc ^ q10) & 7)) * 8];
      f16x8 vd = *(const f16x8*)&x1l[q11 * 128 + ((gc & 8) | ((gc ^ q11) & 7)) * 8];
      const float* sp = &s2l[h * 64 + i * 8];
      f16x8 o8;
#pragma unroll
      for (int j = 0; j < 8; ++j) {
        float v = wy0 * (wx0 * (float)va[j] + wx1 * (float)vb[j])
                + wy1 * (wx0 * (float)vc[j] + wx1 * (float)vd[j]);
        o8[j] = (_Float16)(v * sp[j]);
      }
      *(f16x8*)&xup[pixpad * 64 + ((i ^ (pixpad & 7)) * 8)] = o8;
    }
    __syncthreads();
    for (int kk = 0; kk < 2; ++kk) {
      int kg = h * 2 + kk;
#pragma unroll
      for (int tap = 0; tap < 9; ++tap) {
        int dy = tap / 3, dx = tap - dy * 3;
        f16x8 af[4];
#pragma unroll
        for (int mf = 0; mf < 4; ++mf)
          af[mf] = *(const f16x8*)(w2p + (((tap * 4 + kg) * 4 + mf) * 64 + lane) * 8);
        f16x8 bf[4];
        int g = kk * 4 + (lane >> 4);
#pragma unroll
        for (int nf = 0; nf < 4; ++nf) {
          int pix = (w * 4 + nf + dy) * 18 + (lane & 15) + dx;
          bf[nf] = *(const f16x8*)&xup[pix * 64 + ((g ^ (pix & 7)) * 8)];
        }
#pragma unroll
        for (int mf = 0; mf < 4; ++mf)
#pragma unroll
          for (int nf = 0; nf < 4; ++nf)
            acc[mf][nf] = __builtin_amdgcn_mfma_f32_16x16x32_f16(af[mf], bf[nf], acc[mf][nf], 0, 0, 0);
      }
    }
  }
  int px = lane & 15, r4 = lane >> 4;
#pragma unroll
  for (int mf = 0; mf < 4; ++mf) {
#pragma unroll
    for (int r = 0; r < 4; ++r) {
      int o = mf * 16 + r4 * 4 + r;
      float dm = d2g[b * 64 + o], bias = c2b[o];
#pragma unroll
      for (int nf = 0; nf < 4; ++nf) {
        int py = w * 4 + nf;
        float v = acc[mf][nf][r] * dm + bias;
        v = (v >= 0.f) ? v : 0.2f * v;
        out[(b * 64 + o) * 256 + py * 16 + px] = v;
      }
    }
  }
}

extern "C" void kernel_launch(void* const* d_in, const int* in_sizes, int n_in,
                              void* d_out, int out_size, void* d_ws, size_t ws_size,
                              hipStream_t stream) {
  const float* w    = (const float*)d_in[0];
  const float* ic   = (const float*)d_in[1];
  const float* w0c  = (const float*)d_in[2];
  const float* b0   = (const float*)d_in[3];
  const float* a1w  = (const float*)d_in[4];
  const float* a1b  = (const float*)d_in[5];
  const float* w1c  = (const float*)d_in[6];
  const float* c1b  = (const float*)d_in[7];
  const float* a2w  = (const float*)d_in[8];
  const float* a2b  = (const float*)d_in[9];
  const float* w2c  = (const float*)d_in[10];
  const float* c2b  = (const float*)d_in[11];
  float* out = (float*)d_out;
  char* ws = (char*)d_ws;

  float*    x0u = (float*)(ws + WS_X0U);
  _Float16* Ghp = (_Float16*)(ws + WS_GHP);
  _Float16* w2p = (_Float16*)(ws + WS_W2P);
  float*    afT = (float*)(ws + WS_AFT);
  float*    W2T = (float*)(ws + WS_W2T);
  float*    s   = (float*)(ws + WS_S);
  _Float16* s1p = (_Float16*)(ws + WS_S1P);
  float*    s2  = (float*)(ws + WS_S2);
  float*    d1  = (float*)(ws + WS_D1);
  float*    d2  = (float*)(ws + WS_D2);
  __half*   x1t = (__half*)(ws + WS_X1T);

  k_init <<<256, 64, 0, stream>>>(ic, w0c, b0, x0u);
  k_prep <<<128, 256, 0, stream>>>(w1c, x0u, Ghp);
  k_misc <<<1344, 256, 0, stream>>>(w1c, w2c, a1w, a2w, w2p, afT, W2T);
  dim3 gs(8, 32);
  k_sty  <<<gs, 128, 0, stream>>>(w, afT, a1b, a2b, s, s1p, s2);
  dim3 gd(3, 32);
  k_dmd  <<<gd, 128, 0, stream>>>(s, W2T, d1, d2);
  dim3 g1(64, 16);
  k_l1   <<<g1, 256, 0, stream>>>(s1p, Ghp, d1, c1b, x1t);
  k_l2   <<<2048, 256, 0, stream>>>(x1t, s2, d2, w2p, c2b, out);
}

// Round 4
// 262.842 us; speedup vs baseline: 11.9403x; 1.2063x over previous
//
#include <hip/hip_runtime.h>
#include <hip/hip_fp16.h>

typedef _Float16 f16x8 __attribute__((ext_vector_type(8)));
typedef float f32x4 __attribute__((ext_vector_type(4)));

// ---------------- workspace layout (bytes) ----------------
#define WS_X0U   0            // 256*64*4   = 65536      x0u f32 [c][64]
#define WS_GHP   65536        // 8192*256*2 = 4194304    Ghp f16 frag-packed [n][c]
#define WS_W2P   4259840      // 73728*2    = 147456     w2 f16 frag-packed
#define WS_WH    4407296      // 2048*512*2 = 2097152    w f16 [b][k]
#define WS_AFTH  6504448      // 384*512*2  = 393216     affine wt f16 [f][k]
#define WS_W2TH  6897664      // 192*384*2  = 147456     sum_k W^2 f16 [o][k]
#define WS_S1P   7045120      // 2048*256*2 = 1048576    style1 f16 frag-packed
#define WS_S2H   8093696      // 2048*128*2 = 524288     style2 f16 [b][c]
#define WS_SSQ   8617984      // 2048*384*2 = 1572864    style^2 f16 [b][f]
#define WS_D1    10190848     // 2048*128*4 = 1048576    demod1
#define WS_D2    11239424     // 2048*64*4  = 524288     demod2
#define WS_X1T   11763712     // 2048*64*128*2 = 33554432  x1t f16 [b][p][o]
// end 45318144

// bilinear x2, half-pixel centers
__device__ __forceinline__ void up_wi(int j, int S, int& i0, int& i1,
                                      float& w0, float& w1) {
  int m = j >> 1;
  if (j & 1) { i0 = m; i1 = (m + 1 < S) ? m + 1 : S - 1; w0 = 0.75f; w1 = 0.25f; }
  else       { i0 = (m - 1 >= 0) ? m - 1 : 0; i1 = m;     w0 = 0.25f; w1 = 0.75f; }
}

// ---------------- K0: init conv + lrelu + upsample 4->8 ----------------
__global__ __launch_bounds__(64) void k_init(const float* __restrict__ ic,
    const float* __restrict__ w0c, const float* __restrict__ b0,
    float* __restrict__ x0u) {
  int o = blockIdx.x, t = threadIdx.x;
  __shared__ float part[4][16];
  __shared__ float x4[16];
  int pix = t & 15, cg = t >> 4;
  int py = pix >> 2, px = pix & 3;
  float acc = 0.f;
  for (int c = cg * 128; c < cg * 128 + 128; ++c) {
    const float* wp = w0c + (o * 512 + c) * 9;
    const float* xp = ic + c * 16;
#pragma unroll
    for (int dy = 0; dy < 3; ++dy) {
      int iy = py + dy - 1;
      if ((unsigned)iy >= 4u) continue;
#pragma unroll
      for (int dx = 0; dx < 3; ++dx) {
        int ix = px + dx - 1;
        if ((unsigned)ix >= 4u) continue;
        acc += wp[dy * 3 + dx] * xp[iy * 4 + ix];
      }
    }
  }
  part[cg][pix] = acc;
  __syncthreads();
  if (t < 16) {
    float v = part[0][t] + part[1][t] + part[2][t] + part[3][t] + b0[o];
    x4[t] = (v >= 0.f) ? v : 0.2f * v;
  }
  __syncthreads();
  int oy = t >> 3, ox = t & 7;
  int y0, y1, xx0, xx1; float wy0, wy1, wx0, wx1;
  up_wi(oy, 4, y0, y1, wy0, wy1);
  up_wi(ox, 4, xx0, xx1, wx0, wx1);
  float v = wy0 * (wx0 * x4[y0 * 4 + xx0] + wx1 * x4[y0 * 4 + xx1])
          + wy1 * (wx0 * x4[y1 * 4 + xx0] + wx1 * x4[y1 * 4 + xx1]);
  x0u[o * 64 + t] = v;
}

// ---------------- K_prep: Ghp[n=p*128+o][c] frag-packed f16 --------------
// grid (128 o, 4 pgroup), block 256 (c)
__global__ __launch_bounds__(256) void k_prep(const float* __restrict__ w1c,
    const float* __restrict__ x0u, _Float16* __restrict__ Ghp) {
  int o = blockIdx.x, pg = blockIdx.y, t = threadIdx.x;
  __shared__ _Float16 x0l[256][66];
  for (int i = t; i < 256 * 64; i += 256) {
    int c = i >> 6, p = i & 63;
    x0l[c][p] = (_Float16)x0u[i];
  }
  __syncthreads();
  int c = t;
  float wr9[9];
#pragma unroll
  for (int k = 0; k < 9; ++k) wr9[k] = w1c[(o * 256 + c) * 9 + k];
  int cpart = ((((c >> 3) & 3) * 16 + (o & 15)) * 8) + (c & 7);
  int cq = c >> 5, oq = o >> 4;
  for (int p = pg * 16; p < pg * 16 + 16; ++p) {
    int py = p >> 3, px = p & 7;
    float acc = 0.f;
#pragma unroll
    for (int dy = 0; dy < 3; ++dy) {
      int iy = py + dy - 1;
      if ((unsigned)iy >= 8u) continue;
#pragma unroll
      for (int dx = 0; dx < 3; ++dx) {
        int ix = px + dx - 1;
        if ((unsigned)ix >= 8u) continue;
        acc += wr9[dy * 3 + dx] * (float)x0l[c][iy * 8 + ix];
      }
    }
    Ghp[((p * 8 + oq) * 8 + cq) * 512 + cpart] = (_Float16)acc;
  }
}

// ---------------- K_misc: w2p, wh, afTh, W2Th ----------------------------
// grid 5440, block 256
__global__ __launch_bounds__(256) void k_misc(const float* __restrict__ w1c,
    const float* __restrict__ w2c, const float* __restrict__ a1w,
    const float* __restrict__ a2w, const float* __restrict__ wsrc,
    _Float16* __restrict__ w2p, _Float16* __restrict__ wh,
    _Float16* __restrict__ afTh, _Float16* __restrict__ W2Th) {
  int idx = blockIdx.x * 256 + threadIdx.x;
  if (idx < 73728) {
    int tap = idx / 8192, r = idx & 8191;
    int kg = r >> 11, mf = (r >> 9) & 3, l = (r >> 3) & 63, j = r & 7;
    int o = mf * 16 + (l & 15);
    int c = kg * 32 + (l >> 4) * 8 + j;
    w2p[idx] = (_Float16)w2c[(o * 128 + c) * 9 + tap];
  } else if (idx < 73728 + 1048576) {
    int i = idx - 73728;
    wh[i] = (_Float16)wsrc[i];
  } else if (idx < 73728 + 1048576 + 196608) {
    int i = idx - 73728 - 1048576;         // i = f*512 + k
    afTh[i] = (_Float16)((i < 131072) ? a1w[i] : a2w[i - 131072]);
  } else if (idx < 73728 + 1048576 + 196608 + 73728) {
    int i = idx - 73728 - 1048576 - 196608;  // i = o*384 + k
    int o = i / 384, k = i - o * 384;
    float v = 0.f;
    const float* wp = nullptr;
    if (o < 128 && k < 256)        wp = w1c + (o * 256 + k) * 9;
    else if (o >= 128 && k >= 256) wp = w2c + ((o - 128) * 128 + (k - 256)) * 9;
    if (wp) {
#pragma unroll
      for (int q = 0; q < 9; ++q) v += wp[q] * wp[q];
    }
    W2Th[i] = (_Float16)v;
  }
}

// ---------------- K_sty: styles MFMA GEMM M=2048 N=384 K=512 -------------
// grid (6, 32), block 256 (4 waves 2x2), tile 64x64
__global__ __launch_bounds__(256) void k_sty(const _Float16* __restrict__ wh,
    const _Float16* __restrict__ afTh, const float* __restrict__ a1b,
    const float* __restrict__ a2b, _Float16* __restrict__ s1p,
    _Float16* __restrict__ s2h, _Float16* __restrict__ ssq) {
  int t = threadIdx.x, lane = t & 63, w = t >> 6;
  int wr = w >> 1, wc = w & 1;
  int b0 = blockIdx.y * 64 + wr * 32;
  int f0 = blockIdx.x * 64 + wc * 32;
  f32x4 acc[2][2] = {};
  int lr = lane & 15, lk = (lane >> 4) * 8;
#pragma unroll
  for (int kg = 0; kg < 16; ++kg) {
    f16x8 af[2], bf[2];
#pragma unroll
    for (int mf = 0; mf < 2; ++mf)
      af[mf] = *(const f16x8*)(wh + (b0 + mf * 16 + lr) * 512 + kg * 32 + lk);
#pragma unroll
    for (int nf = 0; nf < 2; ++nf)
      bf[nf] = *(const f16x8*)(afTh + (f0 + nf * 16 + lr) * 512 + kg * 32 + lk);
#pragma unroll
    for (int mf = 0; mf < 2; ++mf)
#pragma unroll
      for (int nf = 0; nf < 2; ++nf)
        acc[mf][nf] = __builtin_amdgcn_mfma_f32_16x16x32_f16(af[mf], bf[nf], acc[mf][nf], 0, 0, 0);
  }
  int r4 = lane >> 4;
#pragma unroll
  for (int nf = 0; nf < 2; ++nf) {
    int f = f0 + nf * 16 + lr;
    float bias = (f < 256) ? a1b[f] : a2b[f - 256];
#pragma unroll
    for (int mf = 0; mf < 2; ++mf) {
#pragma unroll
      for (int r = 0; r < 4; ++r) {
        int b = b0 + mf * 16 + r4 * 4 + r;
        float v = acc[mf][nf][r] + bias;
        ssq[b * 384 + f] = (_Float16)(v * v);
        if (f < 256) {
          int flat = (((b >> 4) * 8 + (f >> 5)) * 64 + ((f >> 3) & 3) * 16 + (b & 15)) * 8 + (f & 7);
          s1p[flat] = (_Float16)v;
        } else {
          s2h[b * 128 + (f - 256)] = (_Float16)v;
        }
      }
    }
  }
}

// ---------------- K_dmd: demod MFMA GEMM M=2048 N=192 K block-sparse -----
// grid (3, 32), block 256, tile 64x64
__global__ __launch_bounds__(256) void k_dmd(const _Float16* __restrict__ ssq,
    const _Float16* __restrict__ W2Th, float* __restrict__ d1,
    float* __restrict__ d2) {
  int t = threadIdx.x, lane = t & 63, w = t >> 6;
  int wr = w >> 1, wc = w & 1;
  int b0 = blockIdx.y * 64 + wr * 32;
  int o0 = blockIdx.x * 64 + wc * 32;
  int kbeg = (blockIdx.x == 2) ? 8 : 0;
  int kend = (blockIdx.x == 2) ? 12 : 8;
  f32x4 acc[2][2] = {};
  int lr = lane & 15, lk = (lane >> 4) * 8;
  for (int kg = kbeg; kg < kend; ++kg) {
    f16x8 af[2], bf[2];
#pragma unroll
    for (int mf = 0; mf < 2; ++mf)
      af[mf] = *(const f16x8*)(ssq + (b0 + mf * 16 + lr) * 384 + kg * 32 + lk);
#pragma unroll
    for (int nf = 0; nf < 2; ++nf)
      bf[nf] = *(const f16x8*)(W2Th + (o0 + nf * 16 + lr) * 384 + kg * 32 + lk);
#pragma unroll
    for (int mf = 0; mf < 2; ++mf)
#pragma unroll
      for (int nf = 0; nf < 2; ++nf)
        acc[mf][nf] = __builtin_amdgcn_mfma_f32_16x16x32_f16(af[mf], bf[nf], acc[mf][nf], 0, 0, 0);
  }
  int r4 = lane >> 4;
#pragma unroll
  for (int mf = 0; mf < 2; ++mf) {
#pragma unroll
    for (int r = 0; r < 4; ++r) {
      int b = b0 + mf * 16 + r4 * 4 + r;
#pragma unroll
      for (int nf = 0; nf < 2; ++nf) {
        int o = o0 + nf * 16 + lr;
        float v = rsqrtf(acc[mf][nf][r] + 1e-8f);
        if (o < 128) d1[b * 128 + o] = v;
        else         d2[b * 64 + (o - 128)] = v;
      }
    }
  }
}

// ---------------- K_l1: MFMA GEMM  M=2048(b) N=8192(p*128+o) K=256 -------
__global__ __launch_bounds__(256) void k_l1(const _Float16* __restrict__ s1p,
    const _Float16* __restrict__ Ghp, const float* __restrict__ d1,
    const float* __restrict__ c1b, __half* __restrict__ x1t) {
  int t = threadIdx.x, lane = t & 63, w = t >> 6;
  int wr = w >> 1, wc = w & 1;
  int bq0 = blockIdx.y * 8 + wr * 4;
  int nq0 = blockIdx.x * 8 + wc * 4;
  f32x4 acc[4][4] = {};
#pragma unroll
  for (int kg = 0; kg < 8; ++kg) {
    f16x8 af[4], bf[4];
#pragma unroll
    for (int mf = 0; mf < 4; ++mf)
      af[mf] = *(const f16x8*)(s1p + (((bq0 + mf) * 8 + kg) * 64 + lane) * 8);
#pragma unroll
    for (int nf = 0; nf < 4; ++nf)
      bf[nf] = *(const f16x8*)(Ghp + (((nq0 + nf) * 8 + kg) * 64 + lane) * 8);
#pragma unroll
    for (int mf = 0; mf < 4; ++mf)
#pragma unroll
      for (int nf = 0; nf < 4; ++nf)
        acc[mf][nf] = __builtin_amdgcn_mfma_f32_16x16x32_f16(af[mf], bf[nf], acc[mf][nf], 0, 0, 0);
  }
  int nc = lane & 15, r4 = lane >> 4;
#pragma unroll
  for (int mf = 0; mf < 4; ++mf) {
#pragma unroll
    for (int r = 0; r < 4; ++r) {
      int b = (bq0 + mf) * 16 + r4 * 4 + r;
#pragma unroll
      for (int nf = 0; nf < 4; ++nf) {
        int n = (nq0 + nf) * 16 + nc;
        int o = n & 127, p = n >> 7;
        float v = acc[mf][nf][r] * d1[b * 128 + o] + c1b[o];
        v = (v >= 0.f) ? v : 0.2f * v;
        x1t[(b * 64 + p) * 128 + o] = (__half)v;
      }
    }
  }
}

// ---------------- K_l2: per-batch upsample+modulate+conv (MFMA) ----------
// grid 2048 (batch), block 256 (4 waves)
__global__ __launch_bounds__(256) void k_l2(const __half* __restrict__ x1t,
    const _Float16* __restrict__ s2h, const float* __restrict__ d2g,
    const _Float16* __restrict__ w2p, const float* __restrict__ c2b,
    float* __restrict__ out) {
  int b = blockIdx.x, t = threadIdx.x;
  int lane = t & 63, w = t >> 6;
  __shared__ unsigned short xup[324 * 64];   // [pix 18x18][64 ch] swizzled 16B granules
  __shared__ unsigned short x1l[64 * 128];   // [q 8x8][128 ch] swizzled
  // stage x1t[b] -> LDS (swizzled granules)
  {
    const __half* src = x1t + b * 8192;
    for (int idx = t; idx < 1024; idx += 256) {
      int q = idx >> 4, gc = idx & 15;
      f16x8 v = *(const f16x8*)(src + q * 128 + gc * 8);
      int gs = (gc & 8) | ((gc ^ q) & 7);
      *(f16x8*)&x1l[q * 128 + gs * 8] = v;
    }
  }
  // zero border ring of xup
  {
    f16x8 z = {};
    for (int idx = t; idx < 68 * 8; idx += 256) {
      int bp = idx >> 3, g = idx & 7;
      int pix;
      if (bp < 18) pix = bp;
      else if (bp < 36) pix = 306 + (bp - 18);
      else { int r = (bp - 36) >> 1; pix = (r + 1) * 18 + ((bp - 36) & 1) * 17; }
      *(f16x8*)&xup[pix * 64 + g * 8] = z;
    }
  }
  // per-thread upsample geometry: one fine pixel per thread
  int fy = t >> 4, fx = t & 15;
  int y0, y1, x0, x1i; float wy0, wy1, wx0, wx1;
  up_wi(fy, 8, y0, y1, wy0, wy1);
  up_wi(fx, 8, x0, x1i, wx0, wx1);
  _Float16 wA = (_Float16)(wy0 * wx0), wB = (_Float16)(wy0 * wx1);
  _Float16 wC = (_Float16)(wy1 * wx0), wD = (_Float16)(wy1 * wx1);
  int pixpad = (fy + 1) * 18 + (fx + 1);
  int q00 = y0 * 8 + x0, q01 = y0 * 8 + x1i, q10 = y1 * 8 + x0, q11 = y1 * 8 + x1i;
  __syncthreads();

  f32x4 acc[4][4] = {};   // [mf(o)][nf(row)]
  f16x8 afb[3][4];        // 2-step-deep A-fragment prefetch ring
  for (int h = 0; h < 2; ++h) {
    if (h) __syncthreads();
    // prefetch first two af step-groups for this h (latency hides under build)
#pragma unroll
    for (int s = 0; s < 2; ++s) {
      int kg = h * 2, tap = s;   // steps 0,1 are kk=0, taps 0,1
#pragma unroll
      for (int mf = 0; mf < 4; ++mf)
        afb[s][mf] = *(const f16x8*)(w2p + (((tap * 4 + kg) * 4 + mf) * 64 + lane) * 8);
    }
    // build upsampled+modulated interior for channels [h*64, h*64+64), packed f16
#pragma unroll
    for (int i = 0; i < 8; ++i) {
      int gc = h * 8 + i;
      f16x8 va = *(const f16x8*)&x1l[q00 * 128 + ((gc & 8) | ((gc ^ q00) & 7)) * 8];
      f16x8 vb = *(const f16x8*)&x1l[q01 * 128 + ((gc & 8) | ((gc ^ q01) & 7)) * 8];
      f16x8 vc = *(const f16x8*)&x1l[q10 * 128 + ((gc & 8) | ((gc ^ q10) & 7)) * 8];
      f16x8 vd = *(const f16x8*)&x1l[q11 * 128 + ((gc & 8) | ((gc ^ q11) & 7)) * 8];
      f16x8 s8 = *(const f16x8*)(s2h + b * 128 + gc * 8);
      f16x8 v = va * wA;
      v += vb * wB;
      v += vc * wC;
      v += vd * wD;
      v *= s8;
      *(f16x8*)&xup[pixpad * 64 + ((i ^ (pixpad & 7)) * 8)] = v;
    }
    __syncthreads();
    // MFMA: 18 flattened (kk,tap) steps, af prefetched 2 steps ahead
#pragma unroll
    for (int s = 0; s < 18; ++s) {
      int kk = s / 9, tap = s - kk * 9;
      int kg = h * 2 + kk;
      int dy = tap / 3, dx = tap - dy * 3;
      if (s < 16) {
        int sn = s + 2;
        int kkn = sn / 9, tapn = sn - kkn * 9;
        int kgn = h * 2 + kkn;
#pragma unroll
        for (int mf = 0; mf < 4; ++mf)
          afb[(s + 2) % 3][mf] = *(const f16x8*)(w2p + (((tapn * 4 + kgn) * 4 + mf) * 64 + lane) * 8);
      }
      f16x8 bf[4];
      int g = kk * 4 + (lane >> 4);
#pragma unroll
      for (int nf = 0; nf < 4; ++nf) {
        int pix = (w * 4 + nf + dy) * 18 + (lane & 15) + dx;
        bf[nf] = *(const f16x8*)&xup[pix * 64 + ((g ^ (pix & 7)) * 8)];
      }
#pragma unroll
      for (int mf = 0; mf < 4; ++mf)
#pragma unroll
        for (int nf = 0; nf < 4; ++nf)
          acc[mf][nf] = __builtin_amdgcn_mfma_f32_16x16x32_f16(afb[s % 3][mf], bf[nf], acc[mf][nf], 0, 0, 0);
    }
  }
  // epilogue: demod + bias + lrelu, f32 out
  int px = lane & 15, r4 = lane >> 4;
#pragma unroll
  for (int mf = 0; mf < 4; ++mf) {
#pragma unroll
    for (int r = 0; r < 4; ++r) {
      int o = mf * 16 + r4 * 4 + r;
      float dm = d2g[b * 64 + o], bias = c2b[o];
#pragma unroll
      for (int nf = 0; nf < 4; ++nf) {
        int py = w * 4 + nf;
        float v = acc[mf][nf][r] * dm + bias;
        v = (v >= 0.f) ? v : 0.2f * v;
        out[(b * 64 + o) * 256 + py * 16 + px] = v;
      }
    }
  }
}

extern "C" void kernel_launch(void* const* d_in, const int* in_sizes, int n_in,
                              void* d_out, int out_size, void* d_ws, size_t ws_size,
                              hipStream_t stream) {
  const float* w    = (const float*)d_in[0];
  const float* ic   = (const float*)d_in[1];
  const float* w0c  = (const float*)d_in[2];
  const float* b0   = (const float*)d_in[3];
  const float* a1w  = (const float*)d_in[4];
  const float* a1b  = (const float*)d_in[5];
  const float* w1c  = (const float*)d_in[6];
  const float* c1b  = (const float*)d_in[7];
  const float* a2w  = (const float*)d_in[8];
  const float* a2b  = (const float*)d_in[9];
  const float* w2c  = (const float*)d_in[10];
  const float* c2b  = (const float*)d_in[11];
  float* out = (float*)d_out;
  char* ws = (char*)d_ws;

  float*    x0u  = (float*)(ws + WS_X0U);
  _Float16* Ghp  = (_Float16*)(ws + WS_GHP);
  _Float16* w2p  = (_Float16*)(ws + WS_W2P);
  _Float16* wh   = (_Float16*)(ws + WS_WH);
  _Float16* afTh = (_Float16*)(ws + WS_AFTH);
  _Float16* W2Th = (_Float16*)(ws + WS_W2TH);
  _Float16* s1p  = (_Float16*)(ws + WS_S1P);
  _Float16* s2h  = (_Float16*)(ws + WS_S2H);
  _Float16* ssq  = (_Float16*)(ws + WS_SSQ);
  float*    d1   = (float*)(ws + WS_D1);
  float*    d2   = (float*)(ws + WS_D2);
  __half*   x1t  = (__half*)(ws + WS_X1T);

  k_init <<<256, 64, 0, stream>>>(ic, w0c, b0, x0u);
  dim3 gp(128, 4);
  k_prep <<<gp, 256, 0, stream>>>(w1c, x0u, Ghp);
  k_misc <<<5440, 256, 0, stream>>>(w1c, w2c, a1w, a2w, w, w2p, wh, afTh, W2Th);
  dim3 gs(6, 32);
  k_sty  <<<gs, 256, 0, stream>>>(wh, afTh, a1b, a2b, s1p, s2h, ssq);
  dim3 gd(3, 32);
  k_dmd  <<<gd, 256, 0, stream>>>(ssq, W2Th, d1, d2);
  dim3 g1(64, 16);
  k_l1   <<<g1, 256, 0, stream>>>(s1p, Ghp, d1, c1b, x1t);
  k_l2   <<<2048, 256, 0, stream>>>(x1t, s2h, d2, w2p, c2b, out);
}